// Round 3
// baseline (1453.049 us; speedup 1.0000x reference)
//
#include <hip/hip_runtime.h>
#include <hip/hip_bf16.h>

// LightGCN: 3 layers of SpMM on 200000x64 f32 embeddings, 3.2M edges.
// R2: (a) quarter-wave gather SpMM: 16 lanes per row-slice, 4 edges/wave-iter,
//     no shfl in inner loop, x2 unroll (8 edges in flight).
//     (b) two-pass bucketed counting sort for CSR build to kill the 8x
//     write amplification of the single-pass random scatter.

constexpr int NUM_USERS = 100000;
constexpr int NUM_ITEMS = 100000;
constexpr int N_NODES   = NUM_USERS + NUM_ITEMS;   // 200000
constexpr int EMB       = 64;
constexpr int N_EDGES   = 3200000;

constexpr int SCAN_BLOCK = 256;
constexpr int SCAN_ELEMS = 1024;                   // 4 per thread
constexpr int NUM_SCAN_BLOCKS = (N_NODES + SCAN_ELEMS - 1) / SCAN_ELEMS; // 196
constexpr int NBUCK = (N_NODES + 255) >> 8;        // 782 buckets of 256 rows

// ---------------- CSR build: per-row histogram + scan ----------------

__global__ void histogram(const int* __restrict__ row, int* __restrict__ cnt) {
    int e = blockIdx.x * blockDim.x + threadIdx.x;
    if (e >= N_EDGES) return;
    atomicAdd(&cnt[row[e]], 1);
}

__global__ void scan_reduce(const int* __restrict__ cnt, int* __restrict__ partials) {
    __shared__ int lds[SCAN_BLOCK];
    int b = blockIdx.x, t = threadIdx.x;
    int base = b * SCAN_ELEMS + t * 4;
    int s = 0;
#pragma unroll
    for (int k = 0; k < 4; ++k) {
        int i = base + k;
        if (i < N_NODES) s += cnt[i];
    }
    lds[t] = s;
    __syncthreads();
    for (int off = SCAN_BLOCK / 2; off > 0; off >>= 1) {
        if (t < off) lds[t] += lds[t + off];
        __syncthreads();
    }
    if (t == 0) partials[b] = lds[0];
}

__global__ void scan_partials(int* partials) {
    __shared__ int lds[SCAN_BLOCK];
    int t = threadIdx.x;
    int v = (t < NUM_SCAN_BLOCKS) ? partials[t] : 0;
    lds[t] = v;
    __syncthreads();
    for (int off = 1; off < SCAN_BLOCK; off <<= 1) {
        int x = (t >= off) ? lds[t - off] : 0;
        __syncthreads();
        lds[t] += x;
        __syncthreads();
    }
    if (t < NUM_SCAN_BLOCKS) partials[t] = lds[t] - v;   // exclusive
}

__global__ void scan_final(const int* __restrict__ cnt, const int* __restrict__ partials,
                           int* __restrict__ row_start, int* __restrict__ cursor) {
    __shared__ int lds[SCAN_BLOCK];
    int b = blockIdx.x, t = threadIdx.x;
    int base = b * SCAN_ELEMS + t * 4;
    int v[4], pre[4];
    int s = 0;
#pragma unroll
    for (int k = 0; k < 4; ++k) {
        int i = base + k;
        v[k] = (i < N_NODES) ? cnt[i] : 0;
        pre[k] = s;
        s += v[k];
    }
    lds[t] = s;
    __syncthreads();
    for (int off = 1; off < SCAN_BLOCK; off <<= 1) {
        int x = (t >= off) ? lds[t - off] : 0;
        __syncthreads();
        lds[t] += x;
        __syncthreads();
    }
    int thread_excl = lds[t] - s;
    int blockbase = partials[b];
#pragma unroll
    for (int k = 0; k < 4; ++k) {
        int i = base + k;
        if (i < N_NODES) {
            int val = blockbase + thread_excl + pre[k];
            row_start[i] = val;
            cursor[i]    = val;
        }
    }
    if (b == 0 && t == 0) row_start[N_NODES] = N_EDGES;
}

// ---------------- bucket pass (kills write amplification) ----------------

// bcnt[b] = sum of cnt over the bucket's 256 rows
__global__ void bucket_count(const int* __restrict__ cnt, int* __restrict__ bcnt) {
    __shared__ int lds[4];
    int b = blockIdx.x, t = threadIdx.x;            // 256 threads
    int i = b * 256 + t;
    int v = (i < N_NODES) ? cnt[i] : 0;
    for (int off = 32; off > 0; off >>= 1) v += __shfl_down(v, off);
    if ((t & 63) == 0) lds[t >> 6] = v;
    __syncthreads();
    if (t == 0) bcnt[b] = lds[0] + lds[1] + lds[2] + lds[3];
}

// exclusive scan of bcnt (NBUCK=782 <= 1024), single block
__global__ void bucket_scan(const int* __restrict__ bcnt,
                            int* __restrict__ bstart, int* __restrict__ bcur) {
    __shared__ int lds[1024];
    int t = threadIdx.x;
    int v = (t < NBUCK) ? bcnt[t] : 0;
    lds[t] = v;
    __syncthreads();
    for (int off = 1; off < 1024; off <<= 1) {
        int x = (t >= off) ? lds[t - off] : 0;
        __syncthreads();
        lds[t] += x;
        __syncthreads();
    }
    if (t < NBUCK) {
        int ex = lds[t] - v;
        bstart[t] = ex;
        bcur[t]   = ex;
    }
    if (t == 0) bstart[NBUCK] = N_EDGES;
}

// pass A: scatter edges into coarse buckets (write windows ~32KB, L2-hot)
// pack: c in bits 0..17 (c < 2^18), r&255 in bits 18..25
__global__ void bucket_scatter(const int* __restrict__ row, const int* __restrict__ col,
                               const float* __restrict__ w,
                               int* __restrict__ bcur, int2* __restrict__ bucket) {
    int e = blockIdx.x * blockDim.x + threadIdx.x;
    if (e >= N_EDGES) return;
    int r = row[e];
    int b = r >> 8;
    int pos = atomicAdd(&bcur[b], 1);
    unsigned pack = (unsigned)col[e] | ((unsigned)(r & 255) << 18);
    bucket[pos] = make_int2((int)pack, __float_as_int(w[e]));
}

// pass B: within-bucket scatter to exact CSR slot (window ~32KB, L2-hot)
__global__ void bucket_to_csr(const int* __restrict__ bstart,
                              const int2* __restrict__ bucket,
                              int* __restrict__ cursor, int2* __restrict__ sorted) {
    int b = blockIdx.x;
    int lo = bstart[b], hi = bstart[b + 1];
    for (int e = lo + (int)threadIdx.x; e < hi; e += (int)blockDim.x) {
        int2 ed = bucket[e];
        unsigned pack = (unsigned)ed.x;
        int r = (b << 8) + (int)(pack >> 18);
        int c = (int)(pack & 0x3FFFFu);
        int pos = atomicAdd(&cursor[r], 1);
        sorted[pos] = make_int2(c, ed.y);
    }
}

// ---------------- SpMM: quarter-wave per row, 8 edges in flight ----------------

template<bool FIRST, bool WRITE_Y>
__global__ __launch_bounds__(256) void spmm_csr(
    const int* __restrict__ row_start, const int2* __restrict__ sorted,
    const float4* __restrict__ srcA,   // col < NUM_USERS
    const float4* __restrict__ srcB,   // col >= NUM_USERS (pre-offset)
    float4* __restrict__ y, float4* __restrict__ acc)
{
    int lane = threadIdx.x & 63;
    int r = blockIdx.x * 4 + (threadIdx.x >> 6);
    if (r >= N_NODES) return;
    int g = lane >> 4;        // edge slot 0..3
    int s = lane & 15;        // float4 slot within row
    int s0 = row_start[r];
    int s1 = row_start[r + 1];

    float ax = 0.f, ay = 0.f, az = 0.f, aw = 0.f;
    for (int base = s0; base < s1; base += 8) {
        int i0 = base + g;
        int i1 = base + 4 + g;
        int c0 = 0, c1 = 0;
        float w0 = 0.f, w1 = 0.f;
        if (i0 < s1) { int2 e = sorted[i0]; c0 = e.x; w0 = __int_as_float(e.y); }
        if (i1 < s1) { int2 e = sorted[i1]; c1 = e.x; w1 = __int_as_float(e.y); }
        const float4* p0 = (c0 < NUM_USERS) ? srcA : srcB;
        const float4* p1 = (c1 < NUM_USERS) ? srcA : srcB;
        float4 v0 = p0[(size_t)c0 * 16 + s];
        float4 v1 = p1[(size_t)c1 * 16 + s];
        ax = fmaf(w0, v0.x, ax); ay = fmaf(w0, v0.y, ay);
        az = fmaf(w0, v0.z, az); aw = fmaf(w0, v0.w, aw);
        ax = fmaf(w1, v1.x, ax); ay = fmaf(w1, v1.y, ay);
        az = fmaf(w1, v1.z, az); aw = fmaf(w1, v1.w, aw);
    }

    // reduce the 4 edge-groups: lanes {s, s+16, s+32, s+48}
    ax += __shfl_xor(ax, 16); ay += __shfl_xor(ay, 16);
    az += __shfl_xor(az, 16); aw += __shfl_xor(aw, 16);
    ax += __shfl_xor(ax, 32); ay += __shfl_xor(ay, 32);
    az += __shfl_xor(az, 32); aw += __shfl_xor(aw, 32);

    if (g == 0) {
        size_t o = (size_t)r * 16 + s;
        if (WRITE_Y) y[o] = make_float4(ax, ay, az, aw);
        constexpr float sc = 1.0f / 3.0f;
        float4 t = make_float4(ax * sc, ay * sc, az * sc, aw * sc);
        if (FIRST) {
            acc[o] = t;
        } else {
            float4 old = acc[o];
            acc[o] = make_float4(old.x + t.x, old.y + t.y, old.z + t.z, old.w + t.w);
        }
    }
}

// ---------------- fallback (baseline atomic path) ----------------

constexpr int TOT4 = N_NODES * EMB / 4;
constexpr int NU4  = NUM_USERS * EMB / 4;

__global__ void concat_init(const float4* __restrict__ u, const float4* __restrict__ it,
                            float4* __restrict__ cur, float4* __restrict__ acc) {
    int i = blockIdx.x * blockDim.x + threadIdx.x;
    if (i >= TOT4) return;
    cur[i] = (i < NU4) ? u[i] : it[i - NU4];
    acc[i] = make_float4(0.f, 0.f, 0.f, 0.f);
}

__global__ void spmm_scatter(const int* __restrict__ row, const int* __restrict__ col,
                             const float* __restrict__ w, const float* __restrict__ x,
                             float* __restrict__ y) {
    int edge = blockIdx.x * (blockDim.x >> 6) + (threadIdx.x >> 6);
    int lane = threadIdx.x & 63;
    if (edge >= N_EDGES) return;
    atomicAdd(&y[row[edge] * EMB + lane], w[edge] * x[col[edge] * EMB + lane]);
}

__global__ void acc_scale(float4* __restrict__ acc, const float4* __restrict__ nxt) {
    int i = blockIdx.x * blockDim.x + threadIdx.x;
    if (i >= TOT4) return;
    float4 a = acc[i];
    float4 n = nxt[i];
    constexpr float s = 1.0f / 3.0f;
    a.x += n.x * s; a.y += n.y * s; a.z += n.z * s; a.w += n.w * s;
    acc[i] = a;
}

// ---------------- launch ----------------

extern "C" void kernel_launch(void* const* d_in, const int* in_sizes, int n_in,
                              void* d_out, int out_size, void* d_ws, size_t ws_size,
                              hipStream_t stream) {
    const float* user_emb = (const float*)d_in[0];
    const float* item_emb = (const float*)d_in[1];
    const float* edge_w   = (const float*)d_in[2];
    const int*   edge_row = (const int*)d_in[3];
    const int*   edge_col = (const int*)d_in[4];
    float*       out      = (float*)d_out;

    const size_t NBUF = (size_t)N_NODES * EMB;     // 12.8M floats

    float* buf0 = (float*)d_ws;
    float* buf1 = buf0 + NBUF;

    char*  p        = (char*)(buf1 + NBUF);
    int2*  sorted   = (int2*)p;                     p += (size_t)N_EDGES * sizeof(int2);
    int*   cnt      = (int*)p;                      p += (size_t)N_NODES * sizeof(int);
    int*   row_start= (int*)p;                      p += (size_t)(N_NODES + 1) * sizeof(int);
    int*   cursor   = (int*)p;                      p += (size_t)N_NODES * sizeof(int);
    int*   partials = (int*)p;                      p += (size_t)SCAN_BLOCK * sizeof(int);
    int*   bcnt     = (int*)p;                      p += (size_t)NBUCK * sizeof(int);
    int*   bstart   = (int*)p;                      p += (size_t)(NBUCK + 1) * sizeof(int);
    int*   bcur     = (int*)p;                      p += (size_t)NBUCK * sizeof(int);
    size_t need = (size_t)((char*)p - (char*)d_ws);

    // bucket array aliases buf1 (dead before layer-1 writes buf1)
    int2* bucket = (int2*)buf1;

    if (ws_size >= need) {
        // ---- CSR build ----
        hipMemsetAsync(cnt, 0, (size_t)N_NODES * sizeof(int), stream);
        histogram<<<(N_EDGES + 255) / 256, 256, 0, stream>>>(edge_row, cnt);
        scan_reduce<<<NUM_SCAN_BLOCKS, SCAN_BLOCK, 0, stream>>>(cnt, partials);
        scan_partials<<<1, SCAN_BLOCK, 0, stream>>>(partials);
        scan_final<<<NUM_SCAN_BLOCKS, SCAN_BLOCK, 0, stream>>>(cnt, partials, row_start, cursor);
        bucket_count<<<NBUCK, 256, 0, stream>>>(cnt, bcnt);
        bucket_scan<<<1, 1024, 0, stream>>>(bcnt, bstart, bcur);
        bucket_scatter<<<(N_EDGES + 255) / 256, 256, 0, stream>>>(edge_row, edge_col, edge_w,
                                                                  bcur, bucket);
        bucket_to_csr<<<NBUCK, 256, 0, stream>>>(bstart, bucket, cursor, sorted);

        // ---- 3 layers, quarter-wave gather SpMM ----
        int grid = (N_NODES + 3) / 4;                // 4 rows per 256-thread block
        const float4* srcA0 = (const float4*)user_emb;
        const float4* srcB0 = (const float4*)item_emb - (size_t)NUM_USERS * (EMB / 4);
        spmm_csr<true, true><<<grid, 256, 0, stream>>>(row_start, sorted,
                                                       srcA0, srcB0,
                                                       (float4*)buf0, (float4*)out);
        spmm_csr<false, true><<<grid, 256, 0, stream>>>(row_start, sorted,
                                                        (const float4*)buf0, (const float4*)buf0,
                                                        (float4*)buf1, (float4*)out);
        spmm_csr<false, false><<<grid, 256, 0, stream>>>(row_start, sorted,
                                                         (const float4*)buf1, (const float4*)buf1,
                                                         (float4*)buf0, (float4*)out);
    } else {
        // ---- fallback: baseline atomic scatter ----
        {
            int blk = 256, g = (TOT4 + blk - 1) / blk;
            concat_init<<<g, blk, 0, stream>>>((const float4*)user_emb, (const float4*)item_emb,
                                               (float4*)buf0, (float4*)out);
        }
        float* cur = buf0;
        float* nxt = buf1;
        for (int l = 0; l < 3; ++l) {
            hipMemsetAsync(nxt, 0, NBUF * sizeof(float), stream);
            int epb = 256 / 64;
            int g = (N_EDGES + epb - 1) / epb;
            spmm_scatter<<<g, 256, 0, stream>>>(edge_row, edge_col, edge_w, cur, nxt);
            int blk = 256, g2 = (TOT4 + blk - 1) / blk;
            acc_scale<<<g2, blk, 0, stream>>>((float4*)out, (const float4*)nxt);
            float* tmp = cur; cur = nxt; nxt = tmp;
        }
    }
}

// Round 4
// 778.535 us; speedup vs baseline: 1.8664x; 1.8664x over previous
//
#include <hip/hip_runtime.h>
#include <hip/hip_bf16.h>

// LightGCN: 3 layers of SpMM on 200000x64 f32 embeddings, 3.2M edges.
// R3: revert the bucketed sort (R2's bucket_scatter hit atomic contention on
// 782 cursors: 748us, VALUBusy 0.16%). Direct scatter to CSR slots with
// 200000 cursors (measured 250us). Keep quarter-wave gather SpMM, widened
// to 16 edges in flight per wave.

constexpr int NUM_USERS = 100000;
constexpr int NUM_ITEMS = 100000;
constexpr int N_NODES   = NUM_USERS + NUM_ITEMS;   // 200000
constexpr int EMB       = 64;
constexpr int N_EDGES   = 3200000;

constexpr int SCAN_BLOCK = 256;
constexpr int SCAN_ELEMS = 1024;                   // 4 per thread
constexpr int NUM_SCAN_BLOCKS = (N_NODES + SCAN_ELEMS - 1) / SCAN_ELEMS; // 196

// ---------------- CSR build ----------------

__global__ void histogram(const int* __restrict__ row, int* __restrict__ cnt) {
    int e = blockIdx.x * blockDim.x + threadIdx.x;
    if (e >= N_EDGES) return;
    atomicAdd(&cnt[row[e]], 1);
}

__global__ void scan_reduce(const int* __restrict__ cnt, int* __restrict__ partials) {
    __shared__ int lds[SCAN_BLOCK];
    int b = blockIdx.x, t = threadIdx.x;
    int base = b * SCAN_ELEMS + t * 4;
    int s = 0;
#pragma unroll
    for (int k = 0; k < 4; ++k) {
        int i = base + k;
        if (i < N_NODES) s += cnt[i];
    }
    lds[t] = s;
    __syncthreads();
    for (int off = SCAN_BLOCK / 2; off > 0; off >>= 1) {
        if (t < off) lds[t] += lds[t + off];
        __syncthreads();
    }
    if (t == 0) partials[b] = lds[0];
}

__global__ void scan_partials(int* partials) {
    __shared__ int lds[SCAN_BLOCK];
    int t = threadIdx.x;
    int v = (t < NUM_SCAN_BLOCKS) ? partials[t] : 0;
    lds[t] = v;
    __syncthreads();
    for (int off = 1; off < SCAN_BLOCK; off <<= 1) {
        int x = (t >= off) ? lds[t - off] : 0;
        __syncthreads();
        lds[t] += x;
        __syncthreads();
    }
    if (t < NUM_SCAN_BLOCKS) partials[t] = lds[t] - v;   // exclusive
}

__global__ void scan_final(const int* __restrict__ cnt, const int* __restrict__ partials,
                           int* __restrict__ row_start, int* __restrict__ cursor) {
    __shared__ int lds[SCAN_BLOCK];
    int b = blockIdx.x, t = threadIdx.x;
    int base = b * SCAN_ELEMS + t * 4;
    int v[4], pre[4];
    int s = 0;
#pragma unroll
    for (int k = 0; k < 4; ++k) {
        int i = base + k;
        v[k] = (i < N_NODES) ? cnt[i] : 0;
        pre[k] = s;
        s += v[k];
    }
    lds[t] = s;
    __syncthreads();
    for (int off = 1; off < SCAN_BLOCK; off <<= 1) {
        int x = (t >= off) ? lds[t - off] : 0;
        __syncthreads();
        lds[t] += x;
        __syncthreads();
    }
    int thread_excl = lds[t] - s;
    int blockbase = partials[b];
#pragma unroll
    for (int k = 0; k < 4; ++k) {
        int i = base + k;
        if (i < N_NODES) {
            int val = blockbase + thread_excl + pre[k];
            row_start[i] = val;
            cursor[i]    = val;
        }
    }
    if (b == 0 && t == 0) row_start[N_NODES] = N_EDGES;
}

// direct scatter: 200000 cursors -> low contention (measured 250us in R1)
__global__ void scatter_edges(const int* __restrict__ row, const int* __restrict__ col,
                              const float* __restrict__ w,
                              int* __restrict__ cursor, int2* __restrict__ sorted) {
    int e = blockIdx.x * blockDim.x + threadIdx.x;
    if (e >= N_EDGES) return;
    int r = row[e];
    int pos = atomicAdd(&cursor[r], 1);
    sorted[pos] = make_int2(col[e], __float_as_int(w[e]));
}

// ---------------- SpMM: quarter-wave per row, 16 edges in flight ----------------

template<bool FIRST, bool WRITE_Y>
__global__ __launch_bounds__(256) void spmm_csr(
    const int* __restrict__ row_start, const int2* __restrict__ sorted,
    const float4* __restrict__ srcA,   // col < NUM_USERS
    const float4* __restrict__ srcB,   // col >= NUM_USERS (pre-offset)
    float4* __restrict__ y, float4* __restrict__ acc)
{
    int lane = threadIdx.x & 63;
    int r = blockIdx.x * 4 + (threadIdx.x >> 6);
    if (r >= N_NODES) return;
    int g = lane >> 4;        // edge group 0..3
    int s = lane & 15;        // float4 slot within row
    int s0 = row_start[r];
    int s1 = row_start[r + 1];

    float ax = 0.f, ay = 0.f, az = 0.f, aw = 0.f;
    for (int base = s0; base < s1; base += 16) {
        int2 e[4];
#pragma unroll
        for (int k = 0; k < 4; ++k) {
            int idx = base + 4 * k + g;
            e[k] = (idx < s1) ? sorted[idx] : make_int2(0, 0);
        }
#pragma unroll
        for (int k = 0; k < 4; ++k) {
            int   c  = e[k].x;
            float wt = __int_as_float(e[k].y);
            const float4* p = (c < NUM_USERS) ? srcA : srcB;
            float4 v = p[(size_t)c * 16 + s];
            ax = fmaf(wt, v.x, ax); ay = fmaf(wt, v.y, ay);
            az = fmaf(wt, v.z, az); aw = fmaf(wt, v.w, aw);
        }
    }

    // reduce across the 4 edge groups: after both steps all lanes hold the sum
    ax += __shfl_xor(ax, 16); ay += __shfl_xor(ay, 16);
    az += __shfl_xor(az, 16); aw += __shfl_xor(aw, 16);
    ax += __shfl_xor(ax, 32); ay += __shfl_xor(ay, 32);
    az += __shfl_xor(az, 32); aw += __shfl_xor(aw, 32);

    size_t o = (size_t)r * 16 + s;
    if (WRITE_Y && g == 0) y[o] = make_float4(ax, ay, az, aw);
    if (g == 1) {
        constexpr float sc = 1.0f / 3.0f;
        float4 t = make_float4(ax * sc, ay * sc, az * sc, aw * sc);
        if (FIRST) {
            acc[o] = t;
        } else {
            float4 old = acc[o];
            acc[o] = make_float4(old.x + t.x, old.y + t.y, old.z + t.z, old.w + t.w);
        }
    }
}

// ---------------- fallback (baseline atomic path) ----------------

constexpr int TOT4 = N_NODES * EMB / 4;
constexpr int NU4  = NUM_USERS * EMB / 4;

__global__ void concat_init(const float4* __restrict__ u, const float4* __restrict__ it,
                            float4* __restrict__ cur, float4* __restrict__ acc) {
    int i = blockIdx.x * blockDim.x + threadIdx.x;
    if (i >= TOT4) return;
    cur[i] = (i < NU4) ? u[i] : it[i - NU4];
    acc[i] = make_float4(0.f, 0.f, 0.f, 0.f);
}

__global__ void spmm_scatter(const int* __restrict__ row, const int* __restrict__ col,
                             const float* __restrict__ w, const float* __restrict__ x,
                             float* __restrict__ y) {
    int edge = blockIdx.x * (blockDim.x >> 6) + (threadIdx.x >> 6);
    int lane = threadIdx.x & 63;
    if (edge >= N_EDGES) return;
    atomicAdd(&y[row[edge] * EMB + lane], w[edge] * x[col[edge] * EMB + lane]);
}

__global__ void acc_scale(float4* __restrict__ acc, const float4* __restrict__ nxt) {
    int i = blockIdx.x * blockDim.x + threadIdx.x;
    if (i >= TOT4) return;
    float4 a = acc[i];
    float4 n = nxt[i];
    constexpr float s = 1.0f / 3.0f;
    a.x += n.x * s; a.y += n.y * s; a.z += n.z * s; a.w += n.w * s;
    acc[i] = a;
}

// ---------------- launch ----------------

extern "C" void kernel_launch(void* const* d_in, const int* in_sizes, int n_in,
                              void* d_out, int out_size, void* d_ws, size_t ws_size,
                              hipStream_t stream) {
    const float* user_emb = (const float*)d_in[0];
    const float* item_emb = (const float*)d_in[1];
    const float* edge_w   = (const float*)d_in[2];
    const int*   edge_row = (const int*)d_in[3];
    const int*   edge_col = (const int*)d_in[4];
    float*       out      = (float*)d_out;

    const size_t NBUF = (size_t)N_NODES * EMB;     // 12.8M floats

    float* buf0 = (float*)d_ws;
    float* buf1 = buf0 + NBUF;

    char*  p        = (char*)(buf1 + NBUF);
    int2*  sorted   = (int2*)p;                     p += (size_t)N_EDGES * sizeof(int2);
    int*   cnt      = (int*)p;                      p += (size_t)N_NODES * sizeof(int);
    int*   row_start= (int*)p;                      p += (size_t)(N_NODES + 1) * sizeof(int);
    int*   cursor   = (int*)p;                      p += (size_t)N_NODES * sizeof(int);
    int*   partials = (int*)p;                      p += (size_t)SCAN_BLOCK * sizeof(int);
    size_t need = (size_t)((char*)p - (char*)d_ws);

    if (ws_size >= need) {
        // ---- CSR build ----
        hipMemsetAsync(cnt, 0, (size_t)N_NODES * sizeof(int), stream);
        histogram<<<(N_EDGES + 255) / 256, 256, 0, stream>>>(edge_row, cnt);
        scan_reduce<<<NUM_SCAN_BLOCKS, SCAN_BLOCK, 0, stream>>>(cnt, partials);
        scan_partials<<<1, SCAN_BLOCK, 0, stream>>>(partials);
        scan_final<<<NUM_SCAN_BLOCKS, SCAN_BLOCK, 0, stream>>>(cnt, partials, row_start, cursor);
        scatter_edges<<<(N_EDGES + 255) / 256, 256, 0, stream>>>(edge_row, edge_col, edge_w,
                                                                 cursor, sorted);

        // ---- 3 layers, quarter-wave gather SpMM ----
        int grid = (N_NODES + 3) / 4;                // 4 rows per 256-thread block
        const float4* srcA0 = (const float4*)user_emb;
        const float4* srcB0 = (const float4*)item_emb - (size_t)NUM_USERS * (EMB / 4);
        spmm_csr<true, true><<<grid, 256, 0, stream>>>(row_start, sorted,
                                                       srcA0, srcB0,
                                                       (float4*)buf0, (float4*)out);
        spmm_csr<false, true><<<grid, 256, 0, stream>>>(row_start, sorted,
                                                        (const float4*)buf0, (const float4*)buf0,
                                                        (float4*)buf1, (float4*)out);
        spmm_csr<false, false><<<grid, 256, 0, stream>>>(row_start, sorted,
                                                         (const float4*)buf1, (const float4*)buf1,
                                                         (float4*)buf0, (float4*)out);
    } else {
        // ---- fallback: baseline atomic scatter ----
        {
            int blk = 256, g = (TOT4 + blk - 1) / blk;
            concat_init<<<g, blk, 0, stream>>>((const float4*)user_emb, (const float4*)item_emb,
                                               (float4*)buf0, (float4*)out);
        }
        float* cur = buf0;
        float* nxt = buf1;
        for (int l = 0; l < 3; ++l) {
            hipMemsetAsync(nxt, 0, NBUF * sizeof(float), stream);
            int epb = 256 / 64;
            int g = (N_EDGES + epb - 1) / epb;
            spmm_scatter<<<g, 256, 0, stream>>>(edge_row, edge_col, edge_w, cur, nxt);
            int blk = 256, g2 = (TOT4 + blk - 1) / blk;
            acc_scale<<<g2, blk, 0, stream>>>((float4*)out, (const float4*)nxt);
            float* tmp = cur; cur = nxt; nxt = tmp;
        }
    }
}

// Round 5
// 764.402 us; speedup vs baseline: 1.9009x; 1.0185x over previous
//
#include <hip/hip_runtime.h>
#include <hip/hip_bf16.h>

// LightGCN: 3 layers of SpMM on 200000x64 embeddings, 3.2M edges.
// R4: (a) XCD-windowed histogram/scatter: blockIdx%8 -> row window, so each
//     window's CSR lines + cursors live in ONE XCD's L2 -> 8B writes merge
//     into full lines before eviction (R3 scatter: WRITE_SIZE 198MB, 230us).
//     (b) bf16 intermediate embeddings (f32 accumulate): gather volume halves.

constexpr int NUM_USERS = 100000;
constexpr int NUM_ITEMS = 100000;
constexpr int N_NODES   = NUM_USERS + NUM_ITEMS;   // 200000
constexpr int EMB       = 64;
constexpr int N_EDGES   = 3200000;

constexpr int SCAN_BLOCK = 256;
constexpr int SCAN_ELEMS = 1024;                   // 4 per thread
constexpr int NUM_SCAN_BLOCKS = (N_NODES + SCAN_ELEMS - 1) / SCAN_ELEMS; // 196
constexpr int WIN = (N_NODES + 7) / 8;             // 25000 rows per XCD window

// ---------------- bf16 helpers ----------------

__device__ __forceinline__ float bfl(unsigned u) { return __uint_as_float(u << 16); }
__device__ __forceinline__ float bfh(unsigned u) { return __uint_as_float(u & 0xFFFF0000u); }
__device__ __forceinline__ unsigned f2bf(float f) {          // RNE
    unsigned u = __float_as_uint(f);
    return (u + 0x7FFFu + ((u >> 16) & 1u)) >> 16;
}
__device__ __forceinline__ unsigned pk(float lo, float hi) {
    return f2bf(lo) | (f2bf(hi) << 16);
}

// concat(user,item) -> bf16 rows. i = uint4 index (16B out, 32B in).
__global__ void concat_bf16(const float4* __restrict__ u, const float4* __restrict__ it,
                            uint4* __restrict__ ebuf) {
    int i = blockIdx.x * blockDim.x + threadIdx.x;
    if (i >= N_NODES * 8) return;
    const float4* s = (i < NUM_USERS * 8) ? (u + 2 * (size_t)i)
                                          : (it + 2 * ((size_t)i - (size_t)NUM_USERS * 8));
    float4 f0 = s[0], f1 = s[1];
    uint4 o;
    o.x = pk(f0.x, f0.y); o.y = pk(f0.z, f0.w);
    o.z = pk(f1.x, f1.y); o.w = pk(f1.z, f1.w);
    ebuf[i] = o;
}

// ---------------- CSR build (XCD-windowed) ----------------

__global__ void hist_xcd(const int* __restrict__ row, int* __restrict__ cnt) {
    int xcd = blockIdx.x & 7;
    int grp = blockIdx.x >> 3;
    int nt  = (gridDim.x >> 3) * blockDim.x;
    int tid = grp * blockDim.x + threadIdx.x;
    int lo = xcd * WIN;
    int hi = lo + WIN; if (hi > N_NODES) hi = N_NODES;
    for (int e = tid; e < N_EDGES; e += nt) {
        int r = row[e];
        if (r >= lo && r < hi) atomicAdd(&cnt[r], 1);
    }
}

__global__ void scan_reduce(const int* __restrict__ cnt, int* __restrict__ partials) {
    __shared__ int lds[SCAN_BLOCK];
    int b = blockIdx.x, t = threadIdx.x;
    int base = b * SCAN_ELEMS + t * 4;
    int s = 0;
#pragma unroll
    for (int k = 0; k < 4; ++k) {
        int i = base + k;
        if (i < N_NODES) s += cnt[i];
    }
    lds[t] = s;
    __syncthreads();
    for (int off = SCAN_BLOCK / 2; off > 0; off >>= 1) {
        if (t < off) lds[t] += lds[t + off];
        __syncthreads();
    }
    if (t == 0) partials[b] = lds[0];
}

__global__ void scan_partials(int* partials) {
    __shared__ int lds[SCAN_BLOCK];
    int t = threadIdx.x;
    int v = (t < NUM_SCAN_BLOCKS) ? partials[t] : 0;
    lds[t] = v;
    __syncthreads();
    for (int off = 1; off < SCAN_BLOCK; off <<= 1) {
        int x = (t >= off) ? lds[t - off] : 0;
        __syncthreads();
        lds[t] += x;
        __syncthreads();
    }
    if (t < NUM_SCAN_BLOCKS) partials[t] = lds[t] - v;   // exclusive
}

__global__ void scan_final(const int* __restrict__ cnt, const int* __restrict__ partials,
                           int* __restrict__ row_start, int* __restrict__ cursor) {
    __shared__ int lds[SCAN_BLOCK];
    int b = blockIdx.x, t = threadIdx.x;
    int base = b * SCAN_ELEMS + t * 4;
    int v[4], pre[4];
    int s = 0;
#pragma unroll
    for (int k = 0; k < 4; ++k) {
        int i = base + k;
        v[k] = (i < N_NODES) ? cnt[i] : 0;
        pre[k] = s;
        s += v[k];
    }
    lds[t] = s;
    __syncthreads();
    for (int off = 1; off < SCAN_BLOCK; off <<= 1) {
        int x = (t >= off) ? lds[t - off] : 0;
        __syncthreads();
        lds[t] += x;
        __syncthreads();
    }
    int thread_excl = lds[t] - s;
    int blockbase = partials[b];
#pragma unroll
    for (int k = 0; k < 4; ++k) {
        int i = base + k;
        if (i < N_NODES) {
            int val = blockbase + thread_excl + pre[k];
            row_start[i] = val;
            cursor[i]    = val;
        }
    }
    if (b == 0 && t == 0) row_start[N_NODES] = N_EDGES;
}

__global__ void scatter_xcd(const int* __restrict__ row, const int* __restrict__ col,
                            const float* __restrict__ w,
                            int* __restrict__ cursor, int2* __restrict__ sorted) {
    int xcd = blockIdx.x & 7;
    int grp = blockIdx.x >> 3;
    int nt  = (gridDim.x >> 3) * blockDim.x;
    int tid = grp * blockDim.x + threadIdx.x;
    int lo = xcd * WIN;
    int hi = lo + WIN; if (hi > N_NODES) hi = N_NODES;
    for (int e = tid; e < N_EDGES; e += nt) {
        int r = row[e];
        if (r >= lo && r < hi) {
            int pos = atomicAdd(&cursor[r], 1);
            sorted[pos] = make_int2(col[e], __float_as_int(w[e]));
        }
    }
}

// ---------------- SpMM: bf16 gather, 8-lane groups, 16 edges in flight ----------------

template<bool FIRST, bool WRITE_Y>
__global__ __launch_bounds__(256) void spmm_bf16(
    const int* __restrict__ row_start, const int2* __restrict__ sorted,
    const uint4* __restrict__ src,     // bf16 rows: 8 x uint4 per row
    uint4* __restrict__ y,             // bf16 rows out
    float4* __restrict__ acc)          // f32 accumulator (d_out)
{
    int lane = threadIdx.x & 63;
    int r = blockIdx.x * 4 + (threadIdx.x >> 6);
    if (r >= N_NODES) return;
    int g = lane >> 3;        // edge group 0..7
    int s = lane & 7;         // 16B slot within row (8 bf16)
    int s0 = row_start[r];
    int s1 = row_start[r + 1];

    float a0 = 0.f, a1 = 0.f, a2 = 0.f, a3 = 0.f;
    float a4 = 0.f, a5 = 0.f, a6 = 0.f, a7 = 0.f;

    for (int base = s0; base < s1; base += 16) {
        int i0 = base + g;
        int i1 = base + 8 + g;
        if (i0 < s1) {
            int2 e = sorted[i0];
            float wt = __int_as_float(e.y);
            uint4 v = src[(size_t)e.x * 8 + s];
            a0 = fmaf(wt, bfl(v.x), a0); a1 = fmaf(wt, bfh(v.x), a1);
            a2 = fmaf(wt, bfl(v.y), a2); a3 = fmaf(wt, bfh(v.y), a3);
            a4 = fmaf(wt, bfl(v.z), a4); a5 = fmaf(wt, bfh(v.z), a5);
            a6 = fmaf(wt, bfl(v.w), a6); a7 = fmaf(wt, bfh(v.w), a7);
        }
        if (i1 < s1) {
            int2 e = sorted[i1];
            float wt = __int_as_float(e.y);
            uint4 v = src[(size_t)e.x * 8 + s];
            a0 = fmaf(wt, bfl(v.x), a0); a1 = fmaf(wt, bfh(v.x), a1);
            a2 = fmaf(wt, bfl(v.y), a2); a3 = fmaf(wt, bfh(v.y), a3);
            a4 = fmaf(wt, bfl(v.z), a4); a5 = fmaf(wt, bfh(v.z), a5);
            a6 = fmaf(wt, bfl(v.w), a6); a7 = fmaf(wt, bfh(v.w), a7);
        }
    }

    // reduce across the 8 edge groups (lane bits 3,4,5)
#define RED(m) \
    a0 += __shfl_xor(a0, m); a1 += __shfl_xor(a1, m); \
    a2 += __shfl_xor(a2, m); a3 += __shfl_xor(a3, m); \
    a4 += __shfl_xor(a4, m); a5 += __shfl_xor(a5, m); \
    a6 += __shfl_xor(a6, m); a7 += __shfl_xor(a7, m);
    RED(8) RED(16) RED(32)
#undef RED

    if (WRITE_Y && g == 0) {
        uint4 o;
        o.x = pk(a0, a1); o.y = pk(a2, a3);
        o.z = pk(a4, a5); o.w = pk(a6, a7);
        y[(size_t)r * 8 + s] = o;
    }
    if (g == 1) {
        constexpr float sc = 1.0f / 3.0f;
        size_t ob = (size_t)r * 16 + 2 * s;
        if (FIRST) {
            acc[ob]     = make_float4(a0 * sc, a1 * sc, a2 * sc, a3 * sc);
            acc[ob + 1] = make_float4(a4 * sc, a5 * sc, a6 * sc, a7 * sc);
        } else {
            float4 x0 = acc[ob];
            float4 x1 = acc[ob + 1];
            x0.x += a0 * sc; x0.y += a1 * sc; x0.z += a2 * sc; x0.w += a3 * sc;
            x1.x += a4 * sc; x1.y += a5 * sc; x1.z += a6 * sc; x1.w += a7 * sc;
            acc[ob]     = x0;
            acc[ob + 1] = x1;
        }
    }
}

// ---------------- launch ----------------

extern "C" void kernel_launch(void* const* d_in, const int* in_sizes, int n_in,
                              void* d_out, int out_size, void* d_ws, size_t ws_size,
                              hipStream_t stream) {
    const float* user_emb = (const float*)d_in[0];
    const float* item_emb = (const float*)d_in[1];
    const float* edge_w   = (const float*)d_in[2];
    const int*   edge_row = (const int*)d_in[3];
    const int*   edge_col = (const int*)d_in[4];
    float*       out      = (float*)d_out;

    // ws layout: two bf16 embedding buffers + CSR
    char* p = (char*)d_ws;
    uint4* ebuf = (uint4*)p;        p += (size_t)N_NODES * 8 * sizeof(uint4);   // 25.6 MB
    uint4* ybuf = (uint4*)p;        p += (size_t)N_NODES * 8 * sizeof(uint4);   // 25.6 MB
    int2*  sorted = (int2*)p;       p += (size_t)N_EDGES * sizeof(int2);        // 25.6 MB
    int*   cnt = (int*)p;           p += (size_t)N_NODES * sizeof(int);
    int*   row_start = (int*)p;     p += (size_t)(N_NODES + 1) * sizeof(int);
    int*   cursor = (int*)p;        p += (size_t)N_NODES * sizeof(int);
    int*   partials = (int*)p;      p += (size_t)SCAN_BLOCK * sizeof(int);

    hipMemsetAsync(cnt, 0, (size_t)N_NODES * sizeof(int), stream);

    concat_bf16<<<(N_NODES * 8 + 255) / 256, 256, 0, stream>>>(
        (const float4*)user_emb, (const float4*)item_emb, ebuf);

    hist_xcd<<<1024, 256, 0, stream>>>(edge_row, cnt);
    scan_reduce<<<NUM_SCAN_BLOCKS, SCAN_BLOCK, 0, stream>>>(cnt, partials);
    scan_partials<<<1, SCAN_BLOCK, 0, stream>>>(partials);
    scan_final<<<NUM_SCAN_BLOCKS, SCAN_BLOCK, 0, stream>>>(cnt, partials, row_start, cursor);
    scatter_xcd<<<1024, 256, 0, stream>>>(edge_row, edge_col, edge_w, cursor, sorted);

    int grid = (N_NODES + 3) / 4;                  // 4 rows per 256-thread block
    // layer 0: ebuf -> ybuf
    spmm_bf16<true, true><<<grid, 256, 0, stream>>>(row_start, sorted, ebuf, ybuf, (float4*)out);
    // layer 1: ybuf -> ebuf (ebuf dead after layer 0)
    spmm_bf16<false, true><<<grid, 256, 0, stream>>>(row_start, sorted, ybuf, ebuf, (float4*)out);
    // layer 2: ebuf -> acc only
    spmm_bf16<false, false><<<grid, 256, 0, stream>>>(row_start, sorted, ebuf, ybuf, (float4*)out);
}